// Round 6
// baseline (766.303 us; speedup 1.0000x reference)
//
#include <hip/hip_runtime.h>
#include <hip/hip_bf16.h>

typedef _Float16 f16;
typedef f16 v8h __attribute__((ext_vector_type(8)));
typedef float v4f __attribute__((ext_vector_type(4)));
typedef unsigned short u16;

__device__ __forceinline__ u16 f2h(float f) {
  f16 h = (f16)f;
  return __builtin_bit_cast(unsigned short, h);
}
__device__ __forceinline__ float h2f(u16 u) {
  f16 h = __builtin_bit_cast(f16, u);
  return (float)h;
}
#define MFMA16(a, b, c) __builtin_amdgcn_mfma_f32_16x16x32_f16((a), (b), (c), 0, 0, 0)

// ---------------- weight prep: fp32 row-major -> fp16 transposed/padded ----------------
// ws layout (u16 element offsets):
//   WcT  [64][128]  @ 0        (from W_cast 100x50,  zero-pad n>=50, k>=100)
//   Wa0T [256][64]  @ 8192     (from W_a0  50x256,   zero-pad k>=50)
//   Wa1T [400][256] @ 24576    (from W_a1  256x400)
//   Wp0T [256][416] @ 126976   (from W_p0  400x256,  zero-pad k>=400)
//   Wp1T [256][256] @ 233472   (from W_p1  256x256)
//   Wp2T [16][256]  @ 299008   (from W_p2  256x8,    zero-pad n>=8)
__global__ void prep_weights(const float* __restrict__ Wc, const float* __restrict__ Wa0,
                             const float* __restrict__ Wa1, const float* __restrict__ Wp0,
                             const float* __restrict__ Wp1, const float* __restrict__ Wp2,
                             u16* __restrict__ ws) {
  int idx = blockIdx.x * 256 + threadIdx.x;
  float v;
  if (idx < 8192) {
    int n = idx >> 7, k = idx & 127;
    v = (n < 50 && k < 100) ? Wc[k * 50 + n] : 0.f;
  } else if (idx < 24576) {
    int i = idx - 8192; int n = i >> 6, k = i & 63;
    v = (k < 50) ? Wa0[k * 256 + n] : 0.f;
  } else if (idx < 126976) {
    int i = idx - 24576; int n = i >> 8, k = i & 255;
    v = Wa1[k * 400 + n];
  } else if (idx < 233472) {
    int i = idx - 126976; int n = i / 416, k = i - n * 416;
    v = (k < 400) ? Wp0[k * 256 + n] : 0.f;
  } else if (idx < 299008) {
    int i = idx - 233472; int n = i >> 8, k = i & 255;
    v = Wp1[k * 256 + n];
  } else if (idx < 303104) {
    int i = idx - 299008; int n = i >> 8, k = i & 255;
    v = (n < 8) ? Wp2[k * 8 + n] : 0.f;
  } else {
    return;
  }
  ws[idx] = f2h(v);
}

// ---------------- fused actor ----------------
// 512 threads = 8 waves, 64 rows/WG. Waves split the N dimension; every GEMM is
// kb-blocked. a1 runs as 4 single-slot passes so peak live regs ~115.
// amdgpu_waves_per_eu(1,2): the allocator honors the RANGE MAX (R4/R5 evidence:
// launch_bounds min alone leaves the 128-cap + spills). This permits up to 256
// VGPRs spill-free; if actual need <=128 the HW still runs 2 blocks/CU.
// LDS: single 54272 B region, phase ping-pong (identical to R3..R5):
//   sAtt [64][56]  @ 0      sG [64][136] @ 7168 (dead after cast)
//   sX   [64][72]  @ 7168   sH [64][264] @ 16384
//   sY   [64][424] @ 0      sP [64][264] @ 0
__global__ __launch_bounds__(512) __attribute__((amdgpu_waves_per_eu(1, 2)))
void actor_kernel(
    const float* __restrict__ o, const float* __restrict__ g,
    const float* __restrict__ b_cast, const float* __restrict__ b_a0,
    const float* __restrict__ b_a1, const float* __restrict__ b_p0,
    const float* __restrict__ b_p1, const float* __restrict__ b_p2,
    const u16* __restrict__ wsb, float* __restrict__ out) {
  __shared__ __align__(16) char smem[54272];
  u16* sAtt = (u16*)smem;            // [64][56]
  u16* sG   = (u16*)(smem + 7168);   // [64][136]
  u16* sX   = (u16*)(smem + 7168);   // [64][72]
  u16* sH   = (u16*)(smem + 16384);  // [64][264]
  u16* sY   = (u16*)smem;            // [64][424]
  u16* sP   = (u16*)smem;            // [64][264]

  const u16* WcT  = wsb;             // [64][128]
  const u16* Wa0T = wsb + 8192;      // [256][64]
  const u16* Wa1T = wsb + 24576;     // [400][256]
  const u16* Wp0T = wsb + 126976;    // [256][416]
  const u16* Wp1T = wsb + 233472;    // [256][256]
  const u16* Wp2T = wsb + 299008;    // [16][256]

  const int tid  = threadIdx.x;
  const int lane = tid & 63;
  const int w    = tid >> 6;   // wave 0..7
  const int nl   = lane & 15;  // MFMA m/n index
  const int q    = lane >> 4;  // quad
  const int row0 = blockIdx.x * 64;

  // ---- stage g -> sG (fp16, K zero-padded 100->128); NT: g is single-use ----
  for (int idx = tid; idx < 64 * 128; idx += 512) {
    int r = idx >> 7, c = idx & 127;
    float v = (c < 100) ? __builtin_nontemporal_load(&g[(row0 + r) * 100 + c]) : 0.f;
    sG[r * 136 + c] = f2h(v);
  }
  __syncthreads();

  // ---- attention = sigmoid(g @ W_cast + b_cast); waves 0..3 own nb=w ----
  if (w < 4) {
    const int col = w * 16 + nl;
    v4f acc[4] = {};
#pragma unroll
    for (int kb = 0; kb < 4; ++kb) {
      v8h bh = *(const v8h*)(WcT + col * 128 + kb * 32 + q * 8);
#pragma unroll
      for (int rb = 0; rb < 4; ++rb) {
        v8h a = *(const v8h*)&sG[(rb * 16 + nl) * 136 + kb * 32 + q * 8];
        acc[rb] = MFMA16(a, bh, acc[rb]);
      }
    }
    if (col < 50) {
      float bias = b_cast[col];
#pragma unroll
      for (int rb = 0; rb < 4; ++rb)
#pragma unroll
        for (int rg = 0; rg < 4; ++rg) {
          float v = acc[rb][rg] + bias;
          v = 1.f / (1.f + __expf(-v));
          sAtt[(rb * 16 + q * 4 + rg) * 56 + col] = f2h(v);
        }
    }
  }
  __syncthreads();  // sAtt visible; sG dead

  // ---- x body part (cols 0..19) + zero pad (cols 50..63); NT o loads ----
  for (int idx = tid; idx < 64 * 20; idx += 512) {
    int r = idx / 20, c = idx - r * 20;
    int src = (c < 10) ? c : (c + 120);
    float v = __builtin_nontemporal_load(&o[(row0 + r) * 260 + src]) * h2f(sAtt[r * 56 + c]);
    sX[r * 72 + c] = f2h(v);
  }
  for (int idx = tid; idx < 64 * 14; idx += 512) {
    int r = idx / 14, c = idx - r * 14;
    sX[r * 72 + 50 + c] = 0;
  }

  v4f ysum[4][4];  // [s-slot][rb]; slots: nbv = w + 8*s (<25)
#pragma unroll
  for (int s = 0; s < 4; ++s)
#pragma unroll
    for (int rb = 0; rb < 4; ++rb) ysum[s][rb] = (v4f){};

  // ---- object loop ----
  for (int obj = 0; obj < 8; ++obj) {
    // object part of x (cols 20..49); NT o loads
    for (int idx = tid; idx < 64 * 30; idx += 512) {
      int r = idx / 30, j = idx - r * 30;
      int src = (j < 15) ? (10 + 15 * obj + j) : (125 + 15 * obj + j);
      float v = __builtin_nontemporal_load(&o[(row0 + r) * 260 + src]) * h2f(sAtt[r * 56 + 20 + j]);
      sX[r * 72 + 20 + j] = f2h(v);
    }
    __syncthreads();  // sX ready; also guarantees prev-obj a1 sH reads done

    // h = relu(x @ W_a0 + b_a0)  (K=64, N=256; wave owns cols 2w,2w+1; kb-blocked)
    {
      v4f acc[2][4] = {};
#pragma unroll
      for (int kb = 0; kb < 2; ++kb) {
        v8h b0 = *(const v8h*)(Wa0T + ((w * 2 + 0) * 16 + nl) * 64 + kb * 32 + q * 8);
        v8h b1 = *(const v8h*)(Wa0T + ((w * 2 + 1) * 16 + nl) * 64 + kb * 32 + q * 8);
#pragma unroll
        for (int rb = 0; rb < 4; ++rb) {
          v8h a = *(const v8h*)&sX[(rb * 16 + nl) * 72 + kb * 32 + q * 8];
          acc[0][rb] = MFMA16(a, b0, acc[0][rb]);
          acc[1][rb] = MFMA16(a, b1, acc[1][rb]);
        }
      }
#pragma unroll
      for (int j = 0; j < 2; ++j) {
        int col = (w * 2 + j) * 16 + nl;
        float bias = b_a0[col];
#pragma unroll
        for (int rb = 0; rb < 4; ++rb)
#pragma unroll
          for (int rg = 0; rg < 4; ++rg) {
            float v = acc[j][rb][rg] + bias;
            v = v > 0.f ? v : 0.f;
            sH[(rb * 16 + q * 4 + rg) * 264 + col] = f2h(v);
          }
      }
    }
    __syncthreads();  // sH ready; all sX reads done

    // y += relu(h @ W_a1 + b_a1)  (K=256, N=400; 4 single-slot passes to keep
    // peak live regs ~115: ysum 64 + acc 16 + frags/addressing)
#pragma unroll
    for (int s = 0; s < 4; ++s) {
      const int nbv = w + s * 8;
      if (nbv < 25) {  // wave-uniform
        v4f acc[4] = {};
#pragma unroll
        for (int kb = 0; kb < 8; ++kb) {
          v8h bh = *(const v8h*)(Wa1T + (nbv * 16 + nl) * 256 + kb * 32 + q * 8);
#pragma unroll
          for (int rb = 0; rb < 4; ++rb) {
            v8h a = *(const v8h*)&sH[(rb * 16 + nl) * 264 + kb * 32 + q * 8];
            acc[rb] = MFMA16(a, bh, acc[rb]);
          }
        }
        float bias = b_a1[nbv * 16 + nl];
#pragma unroll
        for (int rb = 0; rb < 4; ++rb)
#pragma unroll
          for (int rg = 0; rg < 4; ++rg) {
            float v = acc[rb][rg] + bias;
            ysum[s][rb][rg] += v > 0.f ? v : 0.f;
          }
      }
    }
    // no barrier: next x-write touches only sX (a1 read sH/global only)
  }
  __syncthreads();  // all a1 reads done; region becomes sY

  // ---- input_pi -> sY (fp16, K padded 400->416) ----
#pragma unroll
  for (int s = 0; s < 4; ++s) {
    int nbv = w + s * 8;
    if (nbv < 25) {
#pragma unroll
      for (int rb = 0; rb < 4; ++rb)
#pragma unroll
        for (int rg = 0; rg < 4; ++rg)
          sY[(rb * 16 + q * 4 + rg) * 424 + nbv * 16 + nl] = f2h(ysum[s][rb][rg]);
    }
  }
  for (int idx = tid; idx < 64 * 16; idx += 512) {
    int r = idx >> 4, c = idx & 15;
    sY[r * 424 + 400 + c] = 0;
  }
  __syncthreads();

  // ---- p0 = relu(y @ W_p0 + b_p0)  (K=416, N=256; kb-blocked, acc in regs) ----
  v4f p0acc[2][4] = {};
#pragma unroll
  for (int kb = 0; kb < 13; ++kb) {
    v8h b0 = *(const v8h*)(Wp0T + ((w * 2 + 0) * 16 + nl) * 416 + kb * 32 + q * 8);
    v8h b1 = *(const v8h*)(Wp0T + ((w * 2 + 1) * 16 + nl) * 416 + kb * 32 + q * 8);
#pragma unroll
    for (int rb = 0; rb < 4; ++rb) {
      v8h a = *(const v8h*)&sY[(rb * 16 + nl) * 424 + kb * 32 + q * 8];
      p0acc[0][rb] = MFMA16(a, b0, p0acc[0][rb]);
      p0acc[1][rb] = MFMA16(a, b1, p0acc[1][rb]);
    }
  }
  __syncthreads();  // all sY reads done; region becomes sP
#pragma unroll
  for (int j = 0; j < 2; ++j) {
    int col = (w * 2 + j) * 16 + nl;
    float bias = b_p0[col];
#pragma unroll
    for (int rb = 0; rb < 4; ++rb)
#pragma unroll
      for (int rg = 0; rg < 4; ++rg) {
        float v = p0acc[j][rb][rg] + bias;
        v = v > 0.f ? v : 0.f;
        sP[(rb * 16 + q * 4 + rg) * 264 + col] = f2h(v);
      }
  }
  __syncthreads();

  // ---- p1 = relu(p0 @ W_p1 + b_p1)  (K=256, N=256; kb-blocked) ----
  v4f p1acc[2][4] = {};
#pragma unroll
  for (int kb = 0; kb < 8; ++kb) {
    v8h b0 = *(const v8h*)(Wp1T + ((w * 2 + 0) * 16 + nl) * 256 + kb * 32 + q * 8);
    v8h b1 = *(const v8h*)(Wp1T + ((w * 2 + 1) * 16 + nl) * 256 + kb * 32 + q * 8);
#pragma unroll
    for (int rb = 0; rb < 4; ++rb) {
      v8h a = *(const v8h*)&sP[(rb * 16 + nl) * 264 + kb * 32 + q * 8];
      p1acc[0][rb] = MFMA16(a, b0, p1acc[0][rb]);
      p1acc[1][rb] = MFMA16(a, b1, p1acc[1][rb]);
    }
  }
  __syncthreads();  // all sP reads done; rewrite in place
#pragma unroll
  for (int j = 0; j < 2; ++j) {
    int col = (w * 2 + j) * 16 + nl;
    float bias = b_p1[col];
#pragma unroll
    for (int rb = 0; rb < 4; ++rb)
#pragma unroll
      for (int rg = 0; rg < 4; ++rg) {
        float v = p1acc[j][rb][rg] + bias;
        v = v > 0.f ? v : 0.f;
        sP[(rb * 16 + q * 4 + rg) * 264 + col] = f2h(v);
      }
  }
  __syncthreads();

  // ---- out = tanh(p1 @ W_p2 + b_p2)  (K=256, N=8; waves 0..3 own rb=w) ----
  if (w < 4) {
    v4f acc = {};
#pragma unroll
    for (int kb = 0; kb < 8; ++kb) {
      v8h a = *(const v8h*)&sP[(w * 16 + nl) * 264 + kb * 32 + q * 8];
      v8h b = *(const v8h*)(Wp2T + nl * 256 + kb * 32 + q * 8);
      acc = MFMA16(a, b, acc);
    }
    if (nl < 8) {
      float bias = b_p2[nl];
#pragma unroll
      for (int rg = 0; rg < 4; ++rg)
        __builtin_nontemporal_store(tanhf(acc[rg] + bias),
                                    &out[(row0 + w * 16 + q * 4 + rg) * 8 + nl]);
    }
  }
}

extern "C" void kernel_launch(void* const* d_in, const int* in_sizes, int n_in,
                              void* d_out, int out_size, void* d_ws, size_t ws_size,
                              hipStream_t stream) {
  const float* o   = (const float*)d_in[0];
  const float* g   = (const float*)d_in[1];
  const float* Wc  = (const float*)d_in[2];
  const float* bc  = (const float*)d_in[3];
  const float* Wa0 = (const float*)d_in[4];
  const float* ba0 = (const float*)d_in[5];
  const float* Wa1 = (const float*)d_in[6];
  const float* ba1 = (const float*)d_in[7];
  const float* Wp0 = (const float*)d_in[8];
  const float* bp0 = (const float*)d_in[9];
  const float* Wp1 = (const float*)d_in[10];
  const float* bp1 = (const float*)d_in[11];
  const float* Wp2 = (const float*)d_in[12];
  const float* bp2 = (const float*)d_in[13];
  u16* ws = (u16*)d_ws;
  float* out = (float*)d_out;

  int rows = in_sizes[0] / 260;  // 65536

  prep_weights<<<1184, 256, 0, stream>>>(Wc, Wa0, Wa1, Wp0, Wp1, Wp2, ws);
  actor_kernel<<<rows / 64, 512, 0, stream>>>(o, g, bc, ba0, ba1, bp0, bp1, bp2, ws, out);
}

// Round 8
// 708.396 us; speedup vs baseline: 1.0817x; 1.0817x over previous
//
#include <hip/hip_runtime.h>
#include <hip/hip_bf16.h>

typedef _Float16 f16;
typedef f16 v8h __attribute__((ext_vector_type(8)));
typedef float v4f __attribute__((ext_vector_type(4)));
typedef unsigned short u16;

__device__ __forceinline__ u16 f2h(float f) {
  f16 h = (f16)f;
  return __builtin_bit_cast(unsigned short, h);
}
__device__ __forceinline__ float h2f(u16 u) {
  f16 h = __builtin_bit_cast(f16, u);
  return (float)h;
}
#define MFMA16(a, b, c) __builtin_amdgcn_mfma_f32_16x16x32_f16((a), (b), (c), 0, 0, 0)

// ---------------- weight prep: fp32 row-major -> fp16 transposed/padded ----------------
// ws layout (u16 element offsets):
//   WcT  [64][128]  @ 0        (from W_cast 100x50,  zero-pad n>=50, k>=100)
//   Wa0T [256][64]  @ 8192     (from W_a0  50x256,   zero-pad k>=50)
//   Wa1T [400][256] @ 24576    (from W_a1  256x400)
//   Wp0T [256][416] @ 126976   (from W_p0  400x256,  zero-pad k>=400)
//   Wp1T [256][256] @ 233472   (from W_p1  256x256)
//   Wp2T [16][256]  @ 299008   (from W_p2  256x8,    zero-pad n>=8)
__global__ void prep_weights(const float* __restrict__ Wc, const float* __restrict__ Wa0,
                             const float* __restrict__ Wa1, const float* __restrict__ Wp0,
                             const float* __restrict__ Wp1, const float* __restrict__ Wp2,
                             u16* __restrict__ ws) {
  int idx = blockIdx.x * 256 + threadIdx.x;
  float v;
  if (idx < 8192) {
    int n = idx >> 7, k = idx & 127;
    v = (n < 50 && k < 100) ? Wc[k * 50 + n] : 0.f;
  } else if (idx < 24576) {
    int i = idx - 8192; int n = i >> 6, k = i & 63;
    v = (k < 50) ? Wa0[k * 256 + n] : 0.f;
  } else if (idx < 126976) {
    int i = idx - 24576; int n = i >> 8, k = i & 255;
    v = Wa1[k * 400 + n];
  } else if (idx < 233472) {
    int i = idx - 126976; int n = i / 416, k = i - n * 416;
    v = (k < 400) ? Wp0[k * 256 + n] : 0.f;
  } else if (idx < 299008) {
    int i = idx - 233472; int n = i >> 8, k = i & 255;
    v = Wp1[k * 256 + n];
  } else if (idx < 303104) {
    int i = idx - 299008; int n = i >> 8, k = i & 255;
    v = (n < 8) ? Wp2[k * 8 + n] : 0.f;
  } else {
    return;
  }
  ws[idx] = f2h(v);
}

// ---------------- fused actor ----------------
// 512 threads = 8 waves, 64 rows/WG. Waves split the N dimension; every GEMM is
// kb-blocked; fp32 ysum (known-correct R4 math).
//
// KEY SIZING DECISION (R4-R6 forensics): the backend pins the VGPR budget to
// the LDS-implied max occupancy and spills to meet it (54 KB LDS -> 2 blk/CU
// -> 4 waves/EU -> 128 VGPRs; launch_bounds/waves_per_eu overrides ignored;
// 0.3-0.5 GB scratch traffic each round). smem is therefore padded to 84 KB
// (> 160KB/2) => 1 block/CU => 2 waves/EU => 256-VGPR budget; demand ~160
// fits spill-free. Measured occupancy was ~8 waves/CU in all rounds anyway,
// so nothing real is lost.
//
// LDS live layout (first 54272 B of the 86016 B block; phase ping-pong):
//   sAtt [64][56]  @ 0      sG [64][136] @ 7168 (dead after cast)
//   sX   [64][72]  @ 7168   sH [64][264] @ 16384
//   sY   [64][424] @ 0      sP [64][264] @ 0
__global__ __launch_bounds__(512) void actor_kernel(
    const float* __restrict__ o, const float* __restrict__ g,
    const float* __restrict__ b_cast, const float* __restrict__ b_a0,
    const float* __restrict__ b_a1, const float* __restrict__ b_p0,
    const float* __restrict__ b_p1, const float* __restrict__ b_p2,
    const u16* __restrict__ wsb, float* __restrict__ out) {
  __shared__ __align__(16) char smem[86016];  // > 80 KB on purpose (see header)
  u16* sAtt = (u16*)smem;            // [64][56]
  u16* sG   = (u16*)(smem + 7168);   // [64][136]
  u16* sX   = (u16*)(smem + 7168);   // [64][72]
  u16* sH   = (u16*)(smem + 16384);  // [64][264]
  u16* sY   = (u16*)smem;            // [64][424]
  u16* sP   = (u16*)smem;            // [64][264]

  const u16* WcT  = wsb;             // [64][128]
  const u16* Wa0T = wsb + 8192;      // [256][64]
  const u16* Wa1T = wsb + 24576;     // [400][256]
  const u16* Wp0T = wsb + 126976;    // [256][416]
  const u16* Wp1T = wsb + 233472;    // [256][256]
  const u16* Wp2T = wsb + 299008;    // [16][256]

  const int tid  = threadIdx.x;
  const int lane = tid & 63;
  const int w    = tid >> 6;   // wave 0..7
  const int nl   = lane & 15;  // MFMA m/n index
  const int q    = lane >> 4;  // quad
  const int row0 = blockIdx.x * 64;

  // ---- stage g -> sG (fp16, K zero-padded 100->128); NT: g is single-use ----
  for (int idx = tid; idx < 64 * 128; idx += 512) {
    int r = idx >> 7, c = idx & 127;
    float v = (c < 100) ? __builtin_nontemporal_load(&g[(row0 + r) * 100 + c]) : 0.f;
    sG[r * 136 + c] = f2h(v);
  }
  __syncthreads();

  // ---- attention = sigmoid(g @ W_cast + b_cast); waves 0..3 own nb=w ----
  if (w < 4) {
    const int col = w * 16 + nl;
    v4f acc[4] = {};
#pragma unroll
    for (int kb = 0; kb < 4; ++kb) {
      v8h bh = *(const v8h*)(WcT + col * 128 + kb * 32 + q * 8);
#pragma unroll
      for (int rb = 0; rb < 4; ++rb) {
        v8h a = *(const v8h*)&sG[(rb * 16 + nl) * 136 + kb * 32 + q * 8];
        acc[rb] = MFMA16(a, bh, acc[rb]);
      }
    }
    if (col < 50) {
      float bias = b_cast[col];
#pragma unroll
      for (int rb = 0; rb < 4; ++rb)
#pragma unroll
        for (int rg = 0; rg < 4; ++rg) {
          float v = acc[rb][rg] + bias;
          v = 1.f / (1.f + __expf(-v));
          sAtt[(rb * 16 + q * 4 + rg) * 56 + col] = f2h(v);
        }
    }
  }
  __syncthreads();  // sAtt visible; sG dead

  // ---- x body part (cols 0..19) + zero pad (cols 50..63); NT o loads ----
  for (int idx = tid; idx < 64 * 20; idx += 512) {
    int r = idx / 20, c = idx - r * 20;
    int src = (c < 10) ? c : (c + 120);
    float v = __builtin_nontemporal_load(&o[(row0 + r) * 260 + src]) * h2f(sAtt[r * 56 + c]);
    sX[r * 72 + c] = f2h(v);
  }
  for (int idx = tid; idx < 64 * 14; idx += 512) {
    int r = idx / 14, c = idx - r * 14;
    sX[r * 72 + 50 + c] = 0;
  }

  v4f ysum[4][4];  // [s-slot][rb]; slot s covers cols nbv = w + 8*s (<25); fp32
#pragma unroll
  for (int s = 0; s < 4; ++s)
#pragma unroll
    for (int rb = 0; rb < 4; ++rb) ysum[s][rb] = (v4f){};

  // ---- object loop ----
  for (int obj = 0; obj < 8; ++obj) {
    // object part of x (cols 20..49); NT o loads
    for (int idx = tid; idx < 64 * 30; idx += 512) {
      int r = idx / 30, j = idx - r * 30;
      int src = (j < 15) ? (10 + 15 * obj + j) : (125 + 15 * obj + j);
      float v = __builtin_nontemporal_load(&o[(row0 + r) * 260 + src]) * h2f(sAtt[r * 56 + 20 + j]);
      sX[r * 72 + 20 + j] = f2h(v);
    }
    __syncthreads();  // sX ready; also guarantees prev-obj a1 sH reads done

    // h = relu(x @ W_a0 + b_a0)  (K=64, N=256; wave owns cols 2w,2w+1; kb-blocked)
    {
      v4f acc[2][4] = {};
#pragma unroll
      for (int kb = 0; kb < 2; ++kb) {
        v8h b0 = *(const v8h*)(Wa0T + ((w * 2 + 0) * 16 + nl) * 64 + kb * 32 + q * 8);
        v8h b1 = *(const v8h*)(Wa0T + ((w * 2 + 1) * 16 + nl) * 64 + kb * 32 + q * 8);
#pragma unroll
        for (int rb = 0; rb < 4; ++rb) {
          v8h a = *(const v8h*)&sX[(rb * 16 + nl) * 72 + kb * 32 + q * 8];
          acc[0][rb] = MFMA16(a, b0, acc[0][rb]);
          acc[1][rb] = MFMA16(a, b1, acc[1][rb]);
        }
      }
#pragma unroll
      for (int j = 0; j < 2; ++j) {
        int col = (w * 2 + j) * 16 + nl;
        float bias = b_a0[col];
#pragma unroll
        for (int rb = 0; rb < 4; ++rb)
#pragma unroll
          for (int rg = 0; rg < 4; ++rg) {
            float v = acc[j][rb][rg] + bias;
            v = v > 0.f ? v : 0.f;
            sH[(rb * 16 + q * 4 + rg) * 264 + col] = f2h(v);
          }
      }
    }
    __syncthreads();  // sH ready; all sX reads done

    // y += relu(h @ W_a1 + b_a1)  (K=256, N=400; 2 passes x 2 slots, kb-blocked;
    // demand ~160 VGPR, fits the 256 budget from 1-block/CU LDS sizing)
#pragma unroll
    for (int p = 0; p < 2; ++p) {
      const int nb0 = w + 16 * p;       // always < 25
      const int nb1 = w + 8 + 16 * p;   // p==1 valid only for w==0
      const bool has1 = (nb1 < 25);     // wave-uniform
      v4f acc0[4] = {}, acc1[4] = {};
#pragma unroll
      for (int kb = 0; kb < 8; ++kb) {
        v8h bh0 = *(const v8h*)(Wa1T + (nb0 * 16 + nl) * 256 + kb * 32 + q * 8);
        v8h bh1;
        if (has1) bh1 = *(const v8h*)(Wa1T + (nb1 * 16 + nl) * 256 + kb * 32 + q * 8);
#pragma unroll
        for (int rb = 0; rb < 4; ++rb) {
          v8h a = *(const v8h*)&sH[(rb * 16 + nl) * 264 + kb * 32 + q * 8];
          acc0[rb] = MFMA16(a, bh0, acc0[rb]);
          if (has1) acc1[rb] = MFMA16(a, bh1, acc1[rb]);
        }
      }
      {
        float bias = b_a1[nb0 * 16 + nl];
#pragma unroll
        for (int rb = 0; rb < 4; ++rb)
#pragma unroll
          for (int rg = 0; rg < 4; ++rg) {
            float v = acc0[rb][rg] + bias;
            ysum[2 * p][rb][rg] += v > 0.f ? v : 0.f;
          }
      }
      if (has1) {
        float bias = b_a1[nb1 * 16 + nl];
#pragma unroll
        for (int rb = 0; rb < 4; ++rb)
#pragma unroll
          for (int rg = 0; rg < 4; ++rg) {
            float v = acc1[rb][rg] + bias;
            ysum[2 * p + 1][rb][rg] += v > 0.f ? v : 0.f;
          }
      }
    }
    // no barrier: next x-write touches only sX (a1 read sH/global only)
  }
  __syncthreads();  // all a1 reads done; region becomes sY

  // ---- input_pi -> sY (fp16, K padded 400->416) ----
#pragma unroll
  for (int s = 0; s < 4; ++s) {
    int nbv = w + s * 8;
    if (nbv < 25) {
#pragma unroll
      for (int rb = 0; rb < 4; ++rb)
#pragma unroll
        for (int rg = 0; rg < 4; ++rg)
          sY[(rb * 16 + q * 4 + rg) * 424 + nbv * 16 + nl] = f2h(ysum[s][rb][rg]);
    }
  }
  for (int idx = tid; idx < 64 * 16; idx += 512) {
    int r = idx >> 4, c = idx & 15;
    sY[r * 424 + 400 + c] = 0;
  }
  __syncthreads();

  // ---- p0 = relu(y @ W_p0 + b_p0)  (K=416, N=256; kb-blocked, acc in regs) ----
  v4f p0acc[2][4] = {};
#pragma unroll
  for (int kb = 0; kb < 13; ++kb) {
    v8h b0 = *(const v8h*)(Wp0T + ((w * 2 + 0) * 16 + nl) * 416 + kb * 32 + q * 8);
    v8h b1 = *(const v8h*)(Wp0T + ((w * 2 + 1) * 16 + nl) * 416 + kb * 32 + q * 8);
#pragma unroll
    for (int rb = 0; rb < 4; ++rb) {
      v8h a = *(const v8h*)&sY[(rb * 16 + nl) * 424 + kb * 32 + q * 8];
      p0acc[0][rb] = MFMA16(a, b0, p0acc[0][rb]);
      p0acc[1][rb] = MFMA16(a, b1, p0acc[1][rb]);
    }
  }
  __syncthreads();  // all sY reads done; region becomes sP
#pragma unroll
  for (int j = 0; j < 2; ++j) {
    int col = (w * 2 + j) * 16 + nl;
    float bias = b_p0[col];
#pragma unroll
    for (int rb = 0; rb < 4; ++rb)
#pragma unroll
      for (int rg = 0; rg < 4; ++rg) {
        float v = p0acc[j][rb][rg] + bias;
        v = v > 0.f ? v : 0.f;
        sP[(rb * 16 + q * 4 + rg) * 264 + col] = f2h(v);
      }
  }
  __syncthreads();

  // ---- p1 = relu(p0 @ W_p1 + b_p1)  (K=256, N=256; kb-blocked) ----
  v4f p1acc[2][4] = {};
#pragma unroll
  for (int kb = 0; kb < 8; ++kb) {
    v8h b0 = *(const v8h*)(Wp1T + ((w * 2 + 0) * 16 + nl) * 256 + kb * 32 + q * 8);
    v8h b1 = *(const v8h*)(Wp1T + ((w * 2 + 1) * 16 + nl) * 256 + kb * 32 + q * 8);
#pragma unroll
    for (int rb = 0; rb < 4; ++rb) {
      v8h a = *(const v8h*)&sP[(rb * 16 + nl) * 264 + kb * 32 + q * 8];
      p1acc[0][rb] = MFMA16(a, b0, p1acc[0][rb]);
      p1acc[1][rb] = MFMA16(a, b1, p1acc[1][rb]);
    }
  }
  __syncthreads();  // all sP reads done; rewrite in place
#pragma unroll
  for (int j = 0; j < 2; ++j) {
    int col = (w * 2 + j) * 16 + nl;
    float bias = b_p1[col];
#pragma unroll
    for (int rb = 0; rb < 4; ++rb)
#pragma unroll
      for (int rg = 0; rg < 4; ++rg) {
        float v = p1acc[j][rb][rg] + bias;
        v = v > 0.f ? v : 0.f;
        sP[(rb * 16 + q * 4 + rg) * 264 + col] = f2h(v);
      }
  }
  __syncthreads();

  // ---- out = tanh(p1 @ W_p2 + b_p2)  (K=256, N=8; waves 0..3 own rb=w) ----
  if (w < 4) {
    v4f acc = {};
#pragma unroll
    for (int kb = 0; kb < 8; ++kb) {
      v8h a = *(const v8h*)&sP[(w * 16 + nl) * 264 + kb * 32 + q * 8];
      v8h b = *(const v8h*)(Wp2T + nl * 256 + kb * 32 + q * 8);
      acc = MFMA16(a, b, acc);
    }
    if (nl < 8) {
      float bias = b_p2[nl];
#pragma unroll
      for (int rg = 0; rg < 4; ++rg)
        __builtin_nontemporal_store(tanhf(acc[rg] + bias),
                                    &out[(row0 + w * 16 + q * 4 + rg) * 8 + nl]);
    }
  }
}

extern "C" void kernel_launch(void* const* d_in, const int* in_sizes, int n_in,
                              void* d_out, int out_size, void* d_ws, size_t ws_size,
                              hipStream_t stream) {
  const float* o   = (const float*)d_in[0];
  const float* g   = (const float*)d_in[1];
  const float* Wc  = (const float*)d_in[2];
  const float* bc  = (const float*)d_in[3];
  const float* Wa0 = (const float*)d_in[4];
  const float* ba0 = (const float*)d_in[5];
  const float* Wa1 = (const float*)d_in[6];
  const float* ba1 = (const float*)d_in[7];
  const float* Wp0 = (const float*)d_in[8];
  const float* bp0 = (const float*)d_in[9];
  const float* Wp1 = (const float*)d_in[10];
  const float* bp1 = (const float*)d_in[11];
  const float* Wp2 = (const float*)d_in[12];
  const float* bp2 = (const float*)d_in[13];
  u16* ws = (u16*)d_ws;
  float* out = (float*)d_out;

  int rows = in_sizes[0] / 260;  // 65536

  prep_weights<<<1184, 256, 0, stream>>>(Wc, Wa0, Wa1, Wp0, Wp1, Wp2, ws);
  actor_kernel<<<rows / 64, 512, 0, stream>>>(o, g, bc, ba0, ba1, bp0, bp1, bp2, ws, out);
}

// Round 9
// 547.011 us; speedup vs baseline: 1.4009x; 1.2950x over previous
//
#include <hip/hip_runtime.h>
#include <hip/hip_bf16.h>

typedef _Float16 f16;
typedef f16 v8h __attribute__((ext_vector_type(8)));
typedef float v4f __attribute__((ext_vector_type(4)));
typedef unsigned short u16;

__device__ __forceinline__ u16 f2h(float f) {
  f16 h = (f16)f;
  return __builtin_bit_cast(unsigned short, h);
}
__device__ __forceinline__ float h2f(u16 u) {
  f16 h = __builtin_bit_cast(f16, u);
  return (float)h;
}
#define MFMA16(a, b, c) __builtin_amdgcn_mfma_f32_16x16x32_f16((a), (b), (c), 0, 0, 0)

// ---------------- weight prep: fp32 row-major -> fp16 transposed/padded ----------------
// ws layout (u16 element offsets):
//   WcT  [64][128]  @ 0        (from W_cast 100x50,  zero-pad n>=50, k>=100)
//   Wa0T [256][64]  @ 8192     (from W_a0  50x256,   zero-pad k>=50)
//   Wa1T [400][256] @ 24576    (from W_a1  256x400)
//   Wp0T [256][416] @ 126976   (from W_p0  400x256,  zero-pad k>=400)
//   Wp1T [256][256] @ 233472   (from W_p1  256x256)
//   Wp2T [16][256]  @ 299008   (from W_p2  256x8,    zero-pad n>=8)
__global__ void prep_weights(const float* __restrict__ Wc, const float* __restrict__ Wa0,
                             const float* __restrict__ Wa1, const float* __restrict__ Wp0,
                             const float* __restrict__ Wp1, const float* __restrict__ Wp2,
                             u16* __restrict__ ws) {
  int idx = blockIdx.x * 256 + threadIdx.x;
  float v;
  if (idx < 8192) {
    int n = idx >> 7, k = idx & 127;
    v = (n < 50 && k < 100) ? Wc[k * 50 + n] : 0.f;
  } else if (idx < 24576) {
    int i = idx - 8192; int n = i >> 6, k = i & 63;
    v = (k < 50) ? Wa0[k * 256 + n] : 0.f;
  } else if (idx < 126976) {
    int i = idx - 24576; int n = i >> 8, k = i & 255;
    v = Wa1[k * 400 + n];
  } else if (idx < 233472) {
    int i = idx - 126976; int n = i / 416, k = i - n * 416;
    v = (k < 400) ? Wp0[k * 256 + n] : 0.f;
  } else if (idx < 299008) {
    int i = idx - 233472; int n = i >> 8, k = i & 255;
    v = Wp1[k * 256 + n];
  } else if (idx < 303104) {
    int i = idx - 299008; int n = i >> 8, k = i & 255;
    v = (n < 8) ? Wp2[k * 8 + n] : 0.f;
  } else {
    return;
  }
  ws[idx] = f2h(v);
}

// ---------------- fused actor ----------------
// 512 threads = 8 waves, 64 rows/WG. Waves split the N dimension; every GEMM is
// kb-blocked.
//
// R4-R8 forensics: the backend will NOT give this kernel >128 VGPRs (all
// occupancy attributes + LDS sizing ignored; it spills instead -> 0.3-0.5 GB
// scratch traffic/round = the entire bottleneck). Fix: remove the demand.
// ysum (64 fp32 VGPRs live across the object loop) now lives in LDS as
// sYacc fp32[64][408] (104 KB). 1 block/CU (measured occupancy was 8 waves/CU
// at 54 KB AND 86 KB LDS, so nothing lost). Peak reg demand ~100 < 128.
//
// LDS map (158720 B static total):
//   region A @0..54272, phase ping-pong (identical to R3..R8):
//     sAtt [64][56]  @ 0      sG [64][136] @ 7168 (dead after cast)
//     sX   [64][72]  @ 7168   sH [64][264] @ 16384
//     sY   [64][424] @ 0      sP [64][264] @ 0
//   region B @54272: sYacc fp32[64][408] -- per-wave-disjoint cols, no races
__global__ __launch_bounds__(512) void actor_kernel(
    const float* __restrict__ o, const float* __restrict__ g,
    const float* __restrict__ b_cast, const float* __restrict__ b_a0,
    const float* __restrict__ b_a1, const float* __restrict__ b_p0,
    const float* __restrict__ b_p1, const float* __restrict__ b_p2,
    const u16* __restrict__ wsb, float* __restrict__ out) {
  __shared__ __align__(16) char smem[158720];
  u16*   sAtt  = (u16*)smem;            // [64][56]
  u16*   sG    = (u16*)(smem + 7168);   // [64][136]
  u16*   sX    = (u16*)(smem + 7168);   // [64][72]
  u16*   sH    = (u16*)(smem + 16384);  // [64][264]
  u16*   sY    = (u16*)smem;            // [64][424]
  u16*   sP    = (u16*)smem;            // [64][264]
  float* sYacc = (float*)(smem + 54272);// [64][408]

  const u16* WcT  = wsb;             // [64][128]
  const u16* Wa0T = wsb + 8192;      // [256][64]
  const u16* Wa1T = wsb + 24576;     // [400][256]
  const u16* Wp0T = wsb + 126976;    // [256][416]
  const u16* Wp1T = wsb + 233472;    // [256][256]
  const u16* Wp2T = wsb + 299008;    // [16][256]

  const int tid  = threadIdx.x;
  const int lane = tid & 63;
  const int w    = tid >> 6;   // wave 0..7
  const int nl   = lane & 15;  // MFMA m/n index
  const int q    = lane >> 4;  // quad
  const int row0 = blockIdx.x * 64;

  // ---- zero the y accumulator (region B) ----
  for (int idx = tid; idx < 64 * 400; idx += 512) {
    int r = idx / 400, c = idx - r * 400;
    sYacc[r * 408 + c] = 0.f;
  }

  // ---- stage g -> sG (fp16, K zero-padded 100->128); NT: g is single-use ----
  for (int idx = tid; idx < 64 * 128; idx += 512) {
    int r = idx >> 7, c = idx & 127;
    float v = (c < 100) ? __builtin_nontemporal_load(&g[(row0 + r) * 100 + c]) : 0.f;
    sG[r * 136 + c] = f2h(v);
  }
  __syncthreads();

  // ---- attention = sigmoid(g @ W_cast + b_cast); waves 0..3 own nb=w ----
  if (w < 4) {
    const int col = w * 16 + nl;
    v4f acc[4] = {};
#pragma unroll
    for (int kb = 0; kb < 4; ++kb) {
      v8h bh = *(const v8h*)(WcT + col * 128 + kb * 32 + q * 8);
#pragma unroll
      for (int rb = 0; rb < 4; ++rb) {
        v8h a = *(const v8h*)&sG[(rb * 16 + nl) * 136 + kb * 32 + q * 8];
        acc[rb] = MFMA16(a, bh, acc[rb]);
      }
    }
    if (col < 50) {
      float bias = b_cast[col];
#pragma unroll
      for (int rb = 0; rb < 4; ++rb)
#pragma unroll
        for (int rg = 0; rg < 4; ++rg) {
          float v = acc[rb][rg] + bias;
          v = 1.f / (1.f + __expf(-v));
          sAtt[(rb * 16 + q * 4 + rg) * 56 + col] = f2h(v);
        }
    }
  }
  __syncthreads();  // sAtt visible; sG dead

  // ---- x body part (cols 0..19) + zero pad (cols 50..63); NT o loads ----
  for (int idx = tid; idx < 64 * 20; idx += 512) {
    int r = idx / 20, c = idx - r * 20;
    int src = (c < 10) ? c : (c + 120);
    float v = __builtin_nontemporal_load(&o[(row0 + r) * 260 + src]) * h2f(sAtt[r * 56 + c]);
    sX[r * 72 + c] = f2h(v);
  }
  for (int idx = tid; idx < 64 * 14; idx += 512) {
    int r = idx / 14, c = idx - r * 14;
    sX[r * 72 + 50 + c] = 0;
  }

  // ---- object loop ----
  for (int obj = 0; obj < 8; ++obj) {
    // object part of x (cols 20..49); NT o loads
    for (int idx = tid; idx < 64 * 30; idx += 512) {
      int r = idx / 30, j = idx - r * 30;
      int src = (j < 15) ? (10 + 15 * obj + j) : (125 + 15 * obj + j);
      float v = __builtin_nontemporal_load(&o[(row0 + r) * 260 + src]) * h2f(sAtt[r * 56 + 20 + j]);
      sX[r * 72 + 20 + j] = f2h(v);
    }
    __syncthreads();  // sX ready; also guarantees prev-obj a1 sH reads done

    // h = relu(x @ W_a0 + b_a0)  (K=64, N=256; wave owns cols 2w,2w+1; kb-blocked)
    {
      v4f acc[2][4] = {};
#pragma unroll
      for (int kb = 0; kb < 2; ++kb) {
        v8h b0 = *(const v8h*)(Wa0T + ((w * 2 + 0) * 16 + nl) * 64 + kb * 32 + q * 8);
        v8h b1 = *(const v8h*)(Wa0T + ((w * 2 + 1) * 16 + nl) * 64 + kb * 32 + q * 8);
#pragma unroll
        for (int rb = 0; rb < 4; ++rb) {
          v8h a = *(const v8h*)&sX[(rb * 16 + nl) * 72 + kb * 32 + q * 8];
          acc[0][rb] = MFMA16(a, b0, acc[0][rb]);
          acc[1][rb] = MFMA16(a, b1, acc[1][rb]);
        }
      }
#pragma unroll
      for (int j = 0; j < 2; ++j) {
        int col = (w * 2 + j) * 16 + nl;
        float bias = b_a0[col];
#pragma unroll
        for (int rb = 0; rb < 4; ++rb)
#pragma unroll
          for (int rg = 0; rg < 4; ++rg) {
            float v = acc[j][rb][rg] + bias;
            v = v > 0.f ? v : 0.f;
            sH[(rb * 16 + q * 4 + rg) * 264 + col] = f2h(v);
          }
      }
    }
    __syncthreads();  // sH ready; all sX reads done

    // y += relu(h @ W_a1 + b_a1)  (K=256, N=400; 2 passes x 2 slots, kb-blocked;
    // accumulate into LDS sYacc -- wave-disjoint cols, no races, no barriers)
#pragma unroll
    for (int p = 0; p < 2; ++p) {
      const int nb0 = w + 16 * p;       // always < 25
      const int nb1 = w + 8 + 16 * p;   // p==1 valid only for w==0
      const bool has1 = (nb1 < 25);     // wave-uniform
      v4f acc0[4] = {}, acc1[4] = {};
#pragma unroll
      for (int kb = 0; kb < 8; ++kb) {
        v8h bh0 = *(const v8h*)(Wa1T + (nb0 * 16 + nl) * 256 + kb * 32 + q * 8);
        v8h bh1;
        if (has1) bh1 = *(const v8h*)(Wa1T + (nb1 * 16 + nl) * 256 + kb * 32 + q * 8);
#pragma unroll
        for (int rb = 0; rb < 4; ++rb) {
          v8h a = *(const v8h*)&sH[(rb * 16 + nl) * 264 + kb * 32 + q * 8];
          acc0[rb] = MFMA16(a, bh0, acc0[rb]);
          if (has1) acc1[rb] = MFMA16(a, bh1, acc1[rb]);
        }
      }
      {
        float bias = b_a1[nb0 * 16 + nl];
        const int col = nb0 * 16 + nl;
#pragma unroll
        for (int rb = 0; rb < 4; ++rb)
#pragma unroll
          for (int rg = 0; rg < 4; ++rg) {
            float v = acc0[rb][rg] + bias;
            v = v > 0.f ? v : 0.f;
            float* p32 = &sYacc[(rb * 16 + q * 4 + rg) * 408 + col];
            *p32 += v;
          }
      }
      if (has1) {
        float bias = b_a1[nb1 * 16 + nl];
        const int col = nb1 * 16 + nl;
#pragma unroll
        for (int rb = 0; rb < 4; ++rb)
#pragma unroll
          for (int rg = 0; rg < 4; ++rg) {
            float v = acc1[rb][rg] + bias;
            v = v > 0.f ? v : 0.f;
            float* p32 = &sYacc[(rb * 16 + q * 4 + rg) * 408 + col];
            *p32 += v;
          }
      }
    }
    // no barrier: next x-write touches only sX (a1 read sH/global + own sYacc cols)
  }
  __syncthreads();  // all a1 reads/writes done; region A becomes sY

  // ---- convert sYacc (fp32) -> sY (fp16, K padded 400->416) ----
  for (int idx = tid; idx < 64 * 416; idx += 512) {
    int r = idx / 416, c = idx - r * 416;
    float v = (c < 400) ? sYacc[r * 408 + c] : 0.f;
    sY[r * 424 + c] = f2h(v);
  }
  __syncthreads();

  // ---- p0 = relu(y @ W_p0 + b_p0)  (K=416, N=256; kb-blocked, acc in regs) ----
  v4f p0acc[2][4] = {};
#pragma unroll
  for (int kb = 0; kb < 13; ++kb) {
    v8h b0 = *(const v8h*)(Wp0T + ((w * 2 + 0) * 16 + nl) * 416 + kb * 32 + q * 8);
    v8h b1 = *(const v8h*)(Wp0T + ((w * 2 + 1) * 16 + nl) * 416 + kb * 32 + q * 8);
#pragma unroll
    for (int rb = 0; rb < 4; ++rb) {
      v8h a = *(const v8h*)&sY[(rb * 16 + nl) * 424 + kb * 32 + q * 8];
      p0acc[0][rb] = MFMA16(a, b0, p0acc[0][rb]);
      p0acc[1][rb] = MFMA16(a, b1, p0acc[1][rb]);
    }
  }
  __syncthreads();  // all sY reads done; region becomes sP
#pragma unroll
  for (int j = 0; j < 2; ++j) {
    int col = (w * 2 + j) * 16 + nl;
    float bias = b_p0[col];
#pragma unroll
    for (int rb = 0; rb < 4; ++rb)
#pragma unroll
      for (int rg = 0; rg < 4; ++rg) {
        float v = p0acc[j][rb][rg] + bias;
        v = v > 0.f ? v : 0.f;
        sP[(rb * 16 + q * 4 + rg) * 264 + col] = f2h(v);
      }
  }
  __syncthreads();

  // ---- p1 = relu(p0 @ W_p1 + b_p1)  (K=256, N=256; kb-blocked) ----
  v4f p1acc[2][4] = {};
#pragma unroll
  for (int kb = 0; kb < 8; ++kb) {
    v8h b0 = *(const v8h*)(Wp1T + ((w * 2 + 0) * 16 + nl) * 256 + kb * 32 + q * 8);
    v8h b1 = *(const v8h*)(Wp1T + ((w * 2 + 1) * 16 + nl) * 256 + kb * 32 + q * 8);
#pragma unroll
    for (int rb = 0; rb < 4; ++rb) {
      v8h a = *(const v8h*)&sP[(rb * 16 + nl) * 264 + kb * 32 + q * 8];
      p1acc[0][rb] = MFMA16(a, b0, p1acc[0][rb]);
      p1acc[1][rb] = MFMA16(a, b1, p1acc[1][rb]);
    }
  }
  __syncthreads();  // all sP reads done; rewrite in place
#pragma unroll
  for (int j = 0; j < 2; ++j) {
    int col = (w * 2 + j) * 16 + nl;
    float bias = b_p1[col];
#pragma unroll
    for (int rb = 0; rb < 4; ++rb)
#pragma unroll
      for (int rg = 0; rg < 4; ++rg) {
        float v = p1acc[j][rb][rg] + bias;
        v = v > 0.f ? v : 0.f;
        sP[(rb * 16 + q * 4 + rg) * 264 + col] = f2h(v);
      }
  }
  __syncthreads();

  // ---- out = tanh(p1 @ W_p2 + b_p2)  (K=256, N=8; waves 0..3 own rb=w) ----
  if (w < 4) {
    v4f acc = {};
#pragma unroll
    for (int kb = 0; kb < 8; ++kb) {
      v8h a = *(const v8h*)&sP[(w * 16 + nl) * 264 + kb * 32 + q * 8];
      v8h b = *(const v8h*)(Wp2T + nl * 256 + kb * 32 + q * 8);
      acc = MFMA16(a, b, acc);
    }
    if (nl < 8) {
      float bias = b_p2[nl];
#pragma unroll
      for (int rg = 0; rg < 4; ++rg)
        __builtin_nontemporal_store(tanhf(acc[rg] + bias),
                                    &out[(row0 + w * 16 + q * 4 + rg) * 8 + nl]);
    }
  }
}

extern "C" void kernel_launch(void* const* d_in, const int* in_sizes, int n_in,
                              void* d_out, int out_size, void* d_ws, size_t ws_size,
                              hipStream_t stream) {
  const float* o   = (const float*)d_in[0];
  const float* g   = (const float*)d_in[1];
  const float* Wc  = (const float*)d_in[2];
  const float* bc  = (const float*)d_in[3];
  const float* Wa0 = (const float*)d_in[4];
  const float* ba0 = (const float*)d_in[5];
  const float* Wa1 = (const float*)d_in[6];
  const float* ba1 = (const float*)d_in[7];
  const float* Wp0 = (const float*)d_in[8];
  const float* bp0 = (const float*)d_in[9];
  const float* Wp1 = (const float*)d_in[10];
  const float* bp1 = (const float*)d_in[11];
  const float* Wp2 = (const float*)d_in[12];
  const float* bp2 = (const float*)d_in[13];
  u16* ws = (u16*)d_ws;
  float* out = (float*)d_out;

  int rows = in_sizes[0] / 260;  // 65536

  prep_weights<<<1184, 256, 0, stream>>>(Wc, Wa0, Wa1, Wp0, Wp1, Wp2, ws);
  actor_kernel<<<rows / 64, 512, 0, stream>>>(o, g, bc, ba0, ba1, bp0, bp1, bp2, ws, out);
}